// Round 6
// baseline (3171.690 us; speedup 1.0000x reference)
//
#include <hip/hip_runtime.h>
#include <stdint.h>

#define NNODES 10000
#define NEDGES 160000
#define DIM    2500
#define NCLS   16
#define KP     2560          // padded feature dim (40 * 64)
#define MP     10240         // padded rows (40 * 256)
#define K2     5120          // concat K for layer GEMMs
#define KT_SEG 40            // K-steps (of 64) per segment within a sweep

typedef __attribute__((ext_vector_type(8))) short short8;
typedef __attribute__((ext_vector_type(4))) float f32x4;
typedef __attribute__((address_space(3))) void as3_void;
typedef const __attribute__((address_space(1))) void as1_cvoid;
typedef unsigned short ushort_t;

__device__ __forceinline__ unsigned short f2bf(float f) {
    unsigned u = __float_as_uint(f);
    u += 0x7FFFu + ((u >> 16) & 1u);            // RNE
    return (unsigned short)(u >> 16);
}
__device__ __forceinline__ float bf2f(unsigned short s) {
    return __uint_as_float(((unsigned)s) << 16);
}

// ---------------- CSR build (edge_index is int32) ----------------
__global__ void k_deg(const int* __restrict__ ei, int* __restrict__ deg) {
    int e = blockIdx.x * blockDim.x + threadIdx.x;
    if (e < NEDGES) atomicAdd(&deg[ei[NEDGES + e]], 1);
}

__global__ void k_scan(const int* __restrict__ deg, int* __restrict__ off) {
    __shared__ int s[1024];
    __shared__ int carryS;
    int t = threadIdx.x;
    if (t == 0) carryS = 0;
    __syncthreads();
    for (int c = 0; c < NNODES; c += 1024) {
        int i = c + t;
        int v = (i < NNODES) ? deg[i] : 0;
        s[t] = v;
        __syncthreads();
        for (int o = 1; o < 1024; o <<= 1) {
            int add = (t >= o) ? s[t - o] : 0;
            __syncthreads();
            s[t] += add;
            __syncthreads();
        }
        int base = carryS;
        if (i < NNODES) off[i] = base + s[t] - v;   // exclusive
        __syncthreads();
        if (t == 1023) carryS += s[1023];
        __syncthreads();
    }
    if (t == 0) off[NNODES] = carryS;
}

__global__ void k_fill(const int* __restrict__ ei, const int* __restrict__ off,
                       int* __restrict__ cur, int* __restrict__ csr) {
    int e = blockIdx.x * blockDim.x + threadIdx.x;
    if (e < NEDGES) {
        int s = ei[e];
        int d = ei[NEDGES + e];
        int p = atomicAdd(&cur[d], 1);
        csr[off[d] + p] = s;
    }
}

// ---------------- x -> hi/lo bf16 planes (padded, pads zeroed) ----------------
__global__ void k_cvt_x(const float* __restrict__ x,
                        unsigned short* __restrict__ hi, unsigned short* __restrict__ lo) {
    long long idx = (long long)blockIdx.x * blockDim.x + threadIdx.x;  // float4 index
    const int C4 = KP / 4;                                             // 640
    if (idx >= (long long)MP * C4) return;
    int row = (int)(idx / C4), c4 = (int)(idx % C4);
    int k = c4 * 4;
    float vv[4] = {0.f, 0.f, 0.f, 0.f};
    if (row < NNODES && k < DIM) {
        float4 v = *(const float4*)(x + (size_t)row * DIM + k);
        vv[0] = v.x; vv[1] = v.y; vv[2] = v.z; vv[3] = v.w;
    }
    unsigned hw[2], lw[2];
    for (int j = 0; j < 2; j++) {
        unsigned short h0 = f2bf(vv[2*j]);     unsigned short l0 = f2bf(vv[2*j]   - bf2f(h0));
        unsigned short h1 = f2bf(vv[2*j+1]);   unsigned short l1 = f2bf(vv[2*j+1] - bf2f(h1));
        hw[j] = (unsigned)h0 | ((unsigned)h1 << 16);
        lw[j] = (unsigned)l0 | ((unsigned)l1 << 16);
    }
    *(uint2*)(hi + (size_t)row * KP + k) = make_uint2(hw[0], hw[1]);
    *(uint2*)(lo + (size_t)row * KP + k) = make_uint2(lw[0], lw[1]);
}

// ---------------- mean aggregation over in-neighbors (2-edge unrolled) ----------------
__global__ __launch_bounds__(320) void k_agg(
    const unsigned short* __restrict__ shi, const unsigned short* __restrict__ slo,
    const int* __restrict__ off, const int* __restrict__ csr, const int* __restrict__ deg,
    unsigned short* __restrict__ mhi, unsigned short* __restrict__ mlo) {
    int d = blockIdx.x;
    int t = threadIdx.x;                     // owns 8 elems at k = t*8
    int s0 = off[d], s1 = off[d + 1];
    float acc[8];
    #pragma unroll
    for (int i = 0; i < 8; i++) acc[i] = 0.f;
    int e = s0;
    for (; e + 2 <= s1; e += 2) {
        int sa = csr[e], sb = csr[e + 1];
        uint4 ha = *((const uint4*)(shi + (size_t)sa * KP) + t);
        uint4 la = *((const uint4*)(slo + (size_t)sa * KP) + t);
        uint4 hb = *((const uint4*)(shi + (size_t)sb * KP) + t);
        uint4 lb = *((const uint4*)(slo + (size_t)sb * KP) + t);
        unsigned hua[4] = {ha.x, ha.y, ha.z, ha.w};
        unsigned lua[4] = {la.x, la.y, la.z, la.w};
        unsigned hub[4] = {hb.x, hb.y, hb.z, hb.w};
        unsigned lub[4] = {lb.x, lb.y, lb.z, lb.w};
        #pragma unroll
        for (int j = 0; j < 4; j++) {
            acc[2*j]   += bf2f((unsigned short)(hua[j] & 0xFFFFu)) + bf2f((unsigned short)(lua[j] & 0xFFFFu))
                        + bf2f((unsigned short)(hub[j] & 0xFFFFu)) + bf2f((unsigned short)(lub[j] & 0xFFFFu));
            acc[2*j+1] += bf2f((unsigned short)(hua[j] >> 16))     + bf2f((unsigned short)(lua[j] >> 16))
                        + bf2f((unsigned short)(hub[j] >> 16))     + bf2f((unsigned short)(lub[j] >> 16));
        }
    }
    for (; e < s1; e++) {
        int s = csr[e];
        uint4 hv = *((const uint4*)(shi + (size_t)s * KP) + t);
        uint4 lv = *((const uint4*)(slo + (size_t)s * KP) + t);
        unsigned hu[4] = {hv.x, hv.y, hv.z, hv.w};
        unsigned lu[4] = {lv.x, lv.y, lv.z, lv.w};
        #pragma unroll
        for (int j = 0; j < 4; j++) {
            acc[2*j]   += bf2f((unsigned short)(hu[j] & 0xFFFFu)) + bf2f((unsigned short)(lu[j] & 0xFFFFu));
            acc[2*j+1] += bf2f((unsigned short)(hu[j] >> 16))     + bf2f((unsigned short)(lu[j] >> 16));
        }
    }
    int dg = deg[d];
    float inv = 1.0f / (float)(dg > 1 ? dg : 1);
    unsigned oh[4], ol[4];
    #pragma unroll
    for (int j = 0; j < 4; j++) {
        float m0 = acc[2*j] * inv, m1 = acc[2*j+1] * inv;
        unsigned short h0 = f2bf(m0); unsigned short l0 = f2bf(m0 - bf2f(h0));
        unsigned short h1 = f2bf(m1); unsigned short l1 = f2bf(m1 - bf2f(h1));
        oh[j] = (unsigned)h0 | ((unsigned)h1 << 16);
        ol[j] = (unsigned)l0 | ((unsigned)l1 << 16);
    }
    *((uint4*)(mhi + (size_t)d * KP) + t) = make_uint4(oh[0], oh[1], oh[2], oh[3]);
    *((uint4*)(mlo + (size_t)d * KP) + t) = make_uint4(ol[0], ol[1], ol[2], ol[3]);
}

// ---------------- W (K x N fp32) -> WT (N x K2, hi/lo bf16), transposed ----------------
__global__ __launch_bounds__(256) void k_cvt_w(const float* __restrict__ W,
                                               unsigned short* __restrict__ wth,
                                               unsigned short* __restrict__ wtl, int seg) {
    __shared__ float tile[64][65];
    int k0 = blockIdx.x * 64, n0 = blockIdx.y * 64;
    int t = threadIdx.x;
    for (int j = 0; j < 16; j++) {
        int lin = t + j * 256;
        int kk = lin >> 6, nn = lin & 63;
        int gk = k0 + kk, gn = n0 + nn;
        tile[kk][nn] = (gk < DIM && gn < DIM) ? W[(size_t)gk * DIM + gn] : 0.f;
    }
    __syncthreads();
    for (int j = 0; j < 16; j++) {
        int lin = t + j * 256;
        int nn = lin >> 6, kk = lin & 63;
        float v = tile[kk][nn];
        unsigned short h = f2bf(v);
        unsigned short l = f2bf(v - bf2f(h));
        size_t o = (size_t)(n0 + nn) * K2 + (size_t)seg * KP + (k0 + kk);
        wth[o] = h;
        wtl[o] = l;
    }
}

// ---------------- 256x256 8-phase GEMM over 3-sweep concatenated K ----------------
// O = relu(A_self*W_self + A_mean*W_neigh + bias) -> hi/lo planes.
// acc = Ah*Bh (sweep0) + Ah*Bl (sweep1) + Al*Bh (sweep2); each sweep sweeps K2.
// Schedule: 4 phases/K-tile, 2 stage-units issued per phase into the other buffer,
// counted vmcnt(4) per phase (provable per-wave accounting; drain only on last tile).
__global__ __launch_bounds__(512) void k_gemm(
    const ushort_t* __restrict__ AsH, const ushort_t* __restrict__ AsL,
    const ushort_t* __restrict__ AmH, const ushort_t* __restrict__ AmL,
    const ushort_t* __restrict__ BH,  const ushort_t* __restrict__ BL,
    const float* __restrict__ bias,
    ushort_t* __restrict__ OH, ushort_t* __restrict__ OL,
    int nt, int ktSweep) {
    __shared__ __align__(16) ushort_t lds[65536];   // 128 KiB: 2 bufs x (A 32K | B 32K)
    char* ldsByte = (char*)lds;
    const int tid  = threadIdx.x;
    const int lane = tid & 63, wave = tid >> 6;
    const int wr = wave >> 2, wc = wave & 3;          // 2M x 4N wave grid
    const int frow = lane & 15, fk = (lane >> 4) & 3;
    const int tm = blockIdx.x / 10, tn = blockIdx.x % 10;

    // ---- staging source offsets (elements within plane), XOR-pre-swizzled
    const int sr = tid >> 3;          // 0..63 = row within unit
    const int sc = tid & 7;
    const int swz = sc ^ (sr & 7);
    const unsigned offA0 = (unsigned)(tm*256 +   0 + sr) * KP + swz*8;
    const unsigned offA1 = (unsigned)(tm*256 + 128 + sr) * KP + swz*8;
    const unsigned offA4 = (unsigned)(tm*256 +  64 + sr) * KP + swz*8;
    const unsigned offA5 = (unsigned)(tm*256 + 192 + sr) * KP + swz*8;
    // B LDS rows are strip-permuted: rL = np*128 + q*32 + (r&31), r = global n offset
    auto bsrc = [&](int rL) {
        int np = rL >> 7, q = (rL >> 5) & 3, w = rL & 31;
        int r = q*64 + np*32 + w;
        return (unsigned)(tn*256 + r) * K2 + (unsigned)(sc ^ (rL & 7)) * 8;
    };
    const unsigned offB2 = bsrc(  0 + sr);
    const unsigned offB3 = bsrc( 64 + sr);
    const unsigned offB6 = bsrc(128 + sr);
    const unsigned offB7 = bsrc(192 + sr);
    const int waveB = wave << 10;     // per-wave 1 KiB slice of each 8 KiB unit

    // ---- ds_read fragment base offsets (bytes within buffer)
    const int q8 = frow & 7;
    int aB[2], bB[2];
    #pragma unroll
    for (int kk = 0; kk < 2; kk++) {
        aB[kk] = (wr*128 + frow)*128 + (((kk*4+fk) ^ q8) << 4);
        bB[kk] = 32768 + (wc*32 + frow)*128 + (((kk*4+fk) ^ q8) << 4);
    }
    // frag addr: A: aB[kk] + mi*2048 ; B: bB[kk] + np*16384 + nj*2048 ; + bufByte

    f32x4 acc[8][4];
    #pragma unroll
    for (int i = 0; i < 8; i++)
        #pragma unroll
        for (int j = 0; j < 4; j++) acc[i][j] = (f32x4){0.f, 0.f, 0.f, 0.f};

    // ---- staging tile state (tile s being staged; s starts at 0 for prologue)
    int sweep = 0, kks = 0;
    const ushort_t *Ap, *Bp; int kcA, kcB;
#define SET_STAGE() do { \
        const ushort_t* Ah_ = (kks < KT_SEG) ? AsH : AmH; \
        const ushort_t* Al_ = (kks < KT_SEG) ? AsL : AmL; \
        Ap = (sweep < 2) ? Ah_ : Al_; \
        Bp = (sweep == 1) ? BL : BH; \
        kcA = ((kks < KT_SEG) ? kks : kks - KT_SEG) * 64; \
        kcB = kks * 64; } while (0)
    SET_STAGE();

#define GLD(OFF, PTR, KC, DSTB) \
    __builtin_amdgcn_global_load_lds((as1_cvoid*)((PTR) + (OFF) + (unsigned)(KC)), \
        (as3_void*)(ldsByte + (DSTB) + waveB), 16, 0, 0)

    // prologue: tile 0 -> buffer 0, unit order 0..7
    GLD(offA0, Ap, kcA, 0);           GLD(offA1, Ap, kcA, 16384);
    GLD(offB2, Bp, kcB, 32768);       GLD(offB3, Bp, kcB, 32768 + 8192);
    GLD(offA4, Ap, kcA, 8192);        GLD(offA5, Ap, kcA, 24576);
    GLD(offB6, Bp, kcB, 32768+16384); GLD(offB7, Bp, kcB, 32768+24576);

#define FRAG_READS(MP, NP) \
    short8 af[4][2], bf[2][2]; \
    _Pragma("unroll") \
    for (int kk = 0; kk < 2; kk++) { \
        _Pragma("unroll") \
        for (int i = 0; i < 4; i++) \
            af[i][kk] = *(const short8*)(ldsByte + bufByte + aB[kk] + ((MP)*4 + i) * 2048); \
        _Pragma("unroll") \
        for (int j = 0; j < 2; j++) \
            bf[j][kk] = *(const short8*)(ldsByte + bufByte + bB[kk] + (NP)*16384 + j*2048); \
    }

#define MFMA16(MP, NP) \
    _Pragma("unroll") \
    for (int kk = 0; kk < 2; kk++) \
        _Pragma("unroll") \
        for (int i = 0; i < 4; i++) \
            _Pragma("unroll") \
            for (int j = 0; j < 2; j++) \
                acc[(MP)*4+i][(NP)*2+j] = __builtin_amdgcn_mfma_f32_16x16x32_bf16( \
                    af[i][kk], bf[j][kk], acc[(MP)*4+i][(NP)*2+j], 0, 0, 0);

#define PH_TAIL() \
    asm volatile("s_waitcnt lgkmcnt(0)" ::: "memory"); \
    __builtin_amdgcn_sched_barrier(0); \
    __builtin_amdgcn_s_setprio(1)

    for (int t = 0; t < nt; t++) {
        const int bufByte = (t & 1) << 16;
        const int stg = 65536 - bufByte;
        const bool doStage = (t + 1 < nt);
        if (doStage) {
            kks++; if (kks == ktSweep) { kks = 0; sweep++; }
            SET_STAGE();
        }
        { // phase 0: (mp=0, np=0); stage units 0,1 (A rows [0,64),[128,192))
            asm volatile("s_waitcnt vmcnt(4)" ::: "memory");
            asm volatile("s_barrier" ::: "memory");
            FRAG_READS(0, 0);
            if (doStage) { GLD(offA0, Ap, kcA, stg + 0); GLD(offA1, Ap, kcA, stg + 16384); }
            PH_TAIL();
            MFMA16(0, 0);
            __builtin_amdgcn_s_setprio(0);
        }
        { // phase 1: (mp=1, np=0); stage units 2,3 (B np0)
            if (doStage) asm volatile("s_waitcnt vmcnt(4)" ::: "memory");
            else         asm volatile("s_waitcnt vmcnt(2)" ::: "memory");
            asm volatile("s_barrier" ::: "memory");
            FRAG_READS(1, 0);
            if (doStage) { GLD(offB2, Bp, kcB, stg + 32768); GLD(offB3, Bp, kcB, stg + 32768 + 8192); }
            PH_TAIL();
            MFMA16(1, 0);
            __builtin_amdgcn_s_setprio(0);
        }
        { // phase 2: (mp=1, np=1); stage units 4,5 (A rows [64,128),[192,256))
            if (doStage) asm volatile("s_waitcnt vmcnt(4)" ::: "memory");
            else         asm volatile("s_waitcnt vmcnt(0)" ::: "memory");
            asm volatile("s_barrier" ::: "memory");
            FRAG_READS(1, 1);
            if (doStage) { GLD(offA4, Ap, kcA, stg + 8192); GLD(offA5, Ap, kcA, stg + 24576); }
            PH_TAIL();
            MFMA16(1, 1);
            __builtin_amdgcn_s_setprio(0);
        }
        { // phase 3: (mp=0, np=1); stage units 6,7 (B np1); no new first-touch -> no wait
            asm volatile("s_barrier" ::: "memory");
            FRAG_READS(0, 1);
            if (doStage) { GLD(offB6, Bp, kcB, stg + 32768+16384); GLD(offB7, Bp, kcB, stg + 32768+24576); }
            PH_TAIL();
            MFMA16(0, 1);
            __builtin_amdgcn_s_setprio(0);
        }
    }

    // ---- epilogue: bias + relu + hi/lo decompose, zero pad cols
    #pragma unroll
    for (int np = 0; np < 2; np++)
        #pragma unroll
        for (int nj = 0; nj < 2; nj++) {
            int ni = np*2 + nj;
            int gn = tn*256 + wc*64 + ni*16 + frow;
            bool valid = gn < DIM;
            float bv = valid ? bias[gn] : 0.f;
            #pragma unroll
            for (int mi = 0; mi < 8; mi++) {
                int gmBase = tm*256 + wr*128 + mi*16 + ((lane >> 4) & 3) * 4;
                #pragma unroll
                for (int rg = 0; rg < 4; rg++) {
                    float v = acc[mi][ni][rg] + bv;
                    v = fmaxf(v, 0.f);
                    if (!valid) v = 0.f;
                    size_t o = (size_t)(gmBase + rg) * KP + gn;
                    unsigned short h = f2bf(v);
                    OH[o] = h;
                    OL[o] = f2bf(v - bf2f(h));
                }
            }
        }
#undef SET_STAGE
#undef GLD
#undef FRAG_READS
#undef MFMA16
#undef PH_TAIL
}

// ---------------- final head: out = h @ Wc2 + bc2 ----------------
__global__ __launch_bounds__(256) void k_head(
    const unsigned short* __restrict__ HH, const unsigned short* __restrict__ HL,
    const float* __restrict__ W, const float* __restrict__ b, float* __restrict__ out) {
    const int m = blockIdx.x;
    const int t = threadIdx.x;
    const unsigned short* rh = HH + (size_t)m * KP;
    const unsigned short* rl = HL + (size_t)m * KP;
    float acc[NCLS];
    #pragma unroll
    for (int c = 0; c < NCLS; c++) acc[c] = 0.f;
    for (int j = 0; j < 5; j++) {
        int k0 = (j * 256 + t) * 2;
        if (k0 >= DIM) continue;
        unsigned hv = *(const unsigned*)(rh + k0);
        unsigned lv = *(const unsigned*)(rl + k0);
        float v0 = bf2f((unsigned short)(hv & 0xFFFFu)) + bf2f((unsigned short)(lv & 0xFFFFu));
        float v1 = bf2f((unsigned short)(hv >> 16)) + bf2f((unsigned short)(lv >> 16));
        const float* w0 = W + (size_t)k0 * NCLS;
        #pragma unroll
        for (int c = 0; c < NCLS; c++) acc[c] += v0 * w0[c] + v1 * w0[NCLS + c];
    }
    #pragma unroll
    for (int o = 32; o > 0; o >>= 1)
        #pragma unroll
        for (int c = 0; c < NCLS; c++) acc[c] += __shfl_down(acc[c], o);
    __shared__ float red[4][NCLS];
    if ((t & 63) == 0)
        #pragma unroll
        for (int c = 0; c < NCLS; c++) red[t >> 6][c] = acc[c];
    __syncthreads();
    if (t < NCLS)
        out[(size_t)m * NCLS + t] = red[0][t] + red[1][t] + red[2][t] + red[3][t] + b[t];
}

extern "C" void kernel_launch(void* const* d_in, const int* in_sizes, int n_in,
                              void* d_out, int out_size, void* d_ws, size_t ws_size,
                              hipStream_t stream) {
    const float* x   = (const float*)d_in[0];
    const int* ei    = (const int*)d_in[1];   // int32 (JAX default x64-disabled)
    const float* W1s = (const float*)d_in[2];
    const float* W1n = (const float*)d_in[3];
    const float* b1  = (const float*)d_in[4];
    const float* W2s = (const float*)d_in[5];
    const float* W2n = (const float*)d_in[6];
    const float* b2  = (const float*)d_in[7];
    const float* Wc1 = (const float*)d_in[8];
    const float* bc1 = (const float*)d_in[9];
    const float* Wc2 = (const float*)d_in[10];
    const float* bc2 = (const float*)d_in[11];

    char* p = (char*)d_ws;
    auto nxt = [&](size_t bytes) -> char* {
        char* r = p;
        p += (bytes + 255) & ~(size_t)255;
        return r;
    };
    const size_t PLB = (size_t)MP * KP * sizeof(unsigned short);   // 52.4 MB
    unsigned short* F0H = (unsigned short*)nxt(PLB);
    unsigned short* F0L = (unsigned short*)nxt(PLB);
    unsigned short* F1H = (unsigned short*)nxt(PLB);
    unsigned short* F1L = (unsigned short*)nxt(PLB);
    unsigned short* FMH = (unsigned short*)nxt(PLB);
    unsigned short* FML = (unsigned short*)nxt(PLB);
    const size_t WTB = (size_t)KP * K2 * sizeof(unsigned short);   // 26.2 MB
    unsigned short* WTH = (unsigned short*)nxt(WTB);
    unsigned short* WTL = (unsigned short*)nxt(WTB);
    int* deg = (int*)nxt(NNODES * 4);
    int* off = (int*)nxt((NNODES + 1) * 4);
    int* cur = (int*)nxt(NNODES * 4);
    int* csr = (int*)nxt(NEDGES * 4);

    hipMemsetAsync(deg, 0, NNODES * 4, stream);
    hipMemsetAsync(cur, 0, NNODES * 4, stream);

    k_deg<<<(NEDGES + 255) / 256, 256, 0, stream>>>(ei, deg);
    k_scan<<<1, 1024, 0, stream>>>(deg, off);
    k_fill<<<(NEDGES + 255) / 256, 256, 0, stream>>>(ei, off, cur, csr);

    k_cvt_x<<<(int)(((size_t)MP * (KP / 4) + 255) / 256), 256, 0, stream>>>(x, F0H, F0L);

    // layer 1
    k_agg<<<NNODES, 320, 0, stream>>>(F0H, F0L, off, csr, deg, FMH, FML);
    k_cvt_w<<<dim3(40, 40), 256, 0, stream>>>(W1s, WTH, WTL, 0);
    k_cvt_w<<<dim3(40, 40), 256, 0, stream>>>(W1n, WTH, WTL, 1);
    k_gemm<<<400, 512, 0, stream>>>(F0H, F0L, FMH, FML, WTH, WTL, b1, F1H, F1L, 240, 80);

    // layer 2
    k_agg<<<NNODES, 320, 0, stream>>>(F1H, F1L, off, csr, deg, FMH, FML);
    k_cvt_w<<<dim3(40, 40), 256, 0, stream>>>(W2s, WTH, WTL, 0);
    k_cvt_w<<<dim3(40, 40), 256, 0, stream>>>(W2n, WTH, WTL, 1);
    k_gemm<<<400, 512, 0, stream>>>(F1H, F1L, FMH, FML, WTH, WTL, b2, F0H, F0L, 240, 80);

    // classifier hidden (kks < 40 always -> mean planes never read; pass valid ptrs)
    k_cvt_w<<<dim3(40, 40), 256, 0, stream>>>(Wc1, WTH, WTL, 0);
    k_gemm<<<400, 512, 0, stream>>>(F0H, F0L, F0H, F0L, WTH, WTL, bc1, F1H, F1L, 120, 40);

    // head
    k_head<<<NNODES, 256, 0, stream>>>(F1H, F1L, Wc2, bc2, (float*)d_out);
}

// Round 7
// 3003.787 us; speedup vs baseline: 1.0559x; 1.0559x over previous
//
#include <hip/hip_runtime.h>
#include <stdint.h>

#define NNODES 10000
#define NEDGES 160000
#define DIM    2500
#define NCLS   16
#define KP     2560          // padded feature dim (40 * 64)
#define MP     10240         // padded rows (80 * 128)
#define K2     5120          // concat K for layer GEMMs
#define GN     20            // N tiles (2560 / 128)
#define KT_SEG 40            // K-steps per segment (2560 / 64)

typedef __attribute__((ext_vector_type(8))) short short8;
typedef __attribute__((ext_vector_type(4))) float f32x4;
typedef __attribute__((address_space(3))) void as3_void;
typedef const __attribute__((address_space(1))) void as1_cvoid;

__device__ __forceinline__ unsigned short f2bf(float f) {
    unsigned u = __float_as_uint(f);
    u += 0x7FFFu + ((u >> 16) & 1u);            // RNE
    return (unsigned short)(u >> 16);
}
__device__ __forceinline__ float bf2f(unsigned short s) {
    return __uint_as_float(((unsigned)s) << 16);
}

// ---------------- CSR build (edge_index is int32) ----------------
__global__ void k_deg(const int* __restrict__ ei, int* __restrict__ deg) {
    int e = blockIdx.x * blockDim.x + threadIdx.x;
    if (e < NEDGES) atomicAdd(&deg[ei[NEDGES + e]], 1);
}

__global__ void k_scan(const int* __restrict__ deg, int* __restrict__ off) {
    __shared__ int s[1024];
    __shared__ int carryS;
    int t = threadIdx.x;
    if (t == 0) carryS = 0;
    __syncthreads();
    for (int c = 0; c < NNODES; c += 1024) {
        int i = c + t;
        int v = (i < NNODES) ? deg[i] : 0;
        s[t] = v;
        __syncthreads();
        for (int o = 1; o < 1024; o <<= 1) {
            int add = (t >= o) ? s[t - o] : 0;
            __syncthreads();
            s[t] += add;
            __syncthreads();
        }
        int base = carryS;
        if (i < NNODES) off[i] = base + s[t] - v;   // exclusive
        __syncthreads();
        if (t == 1023) carryS += s[1023];
        __syncthreads();
    }
    if (t == 0) off[NNODES] = carryS;
}

__global__ void k_fill(const int* __restrict__ ei, const int* __restrict__ off,
                       int* __restrict__ cur, int* __restrict__ csr) {
    int e = blockIdx.x * blockDim.x + threadIdx.x;
    if (e < NEDGES) {
        int s = ei[e];
        int d = ei[NEDGES + e];
        int p = atomicAdd(&cur[d], 1);
        csr[off[d] + p] = s;
    }
}

// ---------------- x -> hi/lo bf16 planes (padded, pads zeroed) ----------------
__global__ void k_cvt_x(const float* __restrict__ x,
                        unsigned short* __restrict__ hi, unsigned short* __restrict__ lo) {
    long long idx = (long long)blockIdx.x * blockDim.x + threadIdx.x;  // float4 index
    const int C4 = KP / 4;                                             // 640
    if (idx >= (long long)MP * C4) return;
    int row = (int)(idx / C4), c4 = (int)(idx % C4);
    int k = c4 * 4;
    float vv[4] = {0.f, 0.f, 0.f, 0.f};
    if (row < NNODES && k < DIM) {
        float4 v = *(const float4*)(x + (size_t)row * DIM + k);
        vv[0] = v.x; vv[1] = v.y; vv[2] = v.z; vv[3] = v.w;
    }
    unsigned hw[2], lw[2];
    for (int j = 0; j < 2; j++) {
        unsigned short h0 = f2bf(vv[2*j]);     unsigned short l0 = f2bf(vv[2*j]   - bf2f(h0));
        unsigned short h1 = f2bf(vv[2*j+1]);   unsigned short l1 = f2bf(vv[2*j+1] - bf2f(h1));
        hw[j] = (unsigned)h0 | ((unsigned)h1 << 16);
        lw[j] = (unsigned)l0 | ((unsigned)l1 << 16);
    }
    *(uint2*)(hi + (size_t)row * KP + k) = make_uint2(hw[0], hw[1]);
    *(uint2*)(lo + (size_t)row * KP + k) = make_uint2(lw[0], lw[1]);
}

// ---------------- mean aggregation over in-neighbors (2-edge unrolled; measured ~-350us) ----------------
__global__ __launch_bounds__(320) void k_agg(
    const unsigned short* __restrict__ shi, const unsigned short* __restrict__ slo,
    const int* __restrict__ off, const int* __restrict__ csr, const int* __restrict__ deg,
    unsigned short* __restrict__ mhi, unsigned short* __restrict__ mlo) {
    int d = blockIdx.x;
    int t = threadIdx.x;                     // owns 8 elems at k = t*8
    int s0 = off[d], s1 = off[d + 1];
    float acc[8];
    #pragma unroll
    for (int i = 0; i < 8; i++) acc[i] = 0.f;
    int e = s0;
    for (; e + 2 <= s1; e += 2) {
        int sa = csr[e], sb = csr[e + 1];
        uint4 ha = *((const uint4*)(shi + (size_t)sa * KP) + t);
        uint4 la = *((const uint4*)(slo + (size_t)sa * KP) + t);
        uint4 hb = *((const uint4*)(shi + (size_t)sb * KP) + t);
        uint4 lb = *((const uint4*)(slo + (size_t)sb * KP) + t);
        unsigned hua[4] = {ha.x, ha.y, ha.z, ha.w};
        unsigned lua[4] = {la.x, la.y, la.z, la.w};
        unsigned hub[4] = {hb.x, hb.y, hb.z, hb.w};
        unsigned lub[4] = {lb.x, lb.y, lb.z, lb.w};
        #pragma unroll
        for (int j = 0; j < 4; j++) {
            acc[2*j]   += bf2f((unsigned short)(hua[j] & 0xFFFFu)) + bf2f((unsigned short)(lua[j] & 0xFFFFu))
                        + bf2f((unsigned short)(hub[j] & 0xFFFFu)) + bf2f((unsigned short)(lub[j] & 0xFFFFu));
            acc[2*j+1] += bf2f((unsigned short)(hua[j] >> 16))     + bf2f((unsigned short)(lua[j] >> 16))
                        + bf2f((unsigned short)(hub[j] >> 16))     + bf2f((unsigned short)(lub[j] >> 16));
        }
    }
    for (; e < s1; e++) {
        int s = csr[e];
        uint4 hv = *((const uint4*)(shi + (size_t)s * KP) + t);
        uint4 lv = *((const uint4*)(slo + (size_t)s * KP) + t);
        unsigned hu[4] = {hv.x, hv.y, hv.z, hv.w};
        unsigned lu[4] = {lv.x, lv.y, lv.z, lv.w};
        #pragma unroll
        for (int j = 0; j < 4; j++) {
            acc[2*j]   += bf2f((unsigned short)(hu[j] & 0xFFFFu)) + bf2f((unsigned short)(lu[j] & 0xFFFFu));
            acc[2*j+1] += bf2f((unsigned short)(hu[j] >> 16))     + bf2f((unsigned short)(lu[j] >> 16));
        }
    }
    int dg = deg[d];
    float inv = 1.0f / (float)(dg > 1 ? dg : 1);
    unsigned oh[4], ol[4];
    #pragma unroll
    for (int j = 0; j < 4; j++) {
        float m0 = acc[2*j] * inv, m1 = acc[2*j+1] * inv;
        unsigned short h0 = f2bf(m0); unsigned short l0 = f2bf(m0 - bf2f(h0));
        unsigned short h1 = f2bf(m1); unsigned short l1 = f2bf(m1 - bf2f(h1));
        oh[j] = (unsigned)h0 | ((unsigned)h1 << 16);
        ol[j] = (unsigned)l0 | ((unsigned)l1 << 16);
    }
    *((uint4*)(mhi + (size_t)d * KP) + t) = make_uint4(oh[0], oh[1], oh[2], oh[3]);
    *((uint4*)(mlo + (size_t)d * KP) + t) = make_uint4(ol[0], ol[1], ol[2], ol[3]);
}

// ---------------- W (K x N fp32) -> WT (N x K2, hi/lo bf16), transposed ----------------
__global__ __launch_bounds__(256) void k_cvt_w(const float* __restrict__ W,
                                               unsigned short* __restrict__ wth,
                                               unsigned short* __restrict__ wtl, int seg) {
    __shared__ float tile[64][65];
    int k0 = blockIdx.x * 64, n0 = blockIdx.y * 64;
    int t = threadIdx.x;
    for (int j = 0; j < 16; j++) {
        int lin = t + j * 256;
        int kk = lin >> 6, nn = lin & 63;
        int gk = k0 + kk, gn = n0 + nn;
        tile[kk][nn] = (gk < DIM && gn < DIM) ? W[(size_t)gk * DIM + gn] : 0.f;
    }
    __syncthreads();
    for (int j = 0; j < 16; j++) {
        int lin = t + j * 256;
        int nn = lin >> 6, kk = lin & 63;
        float v = tile[kk][nn];
        unsigned short h = f2bf(v);
        unsigned short l = f2bf(v - bf2f(h));
        size_t o = (size_t)(n0 + nn) * K2 + (size_t)seg * KP + (k0 + kk);
        wth[o] = h;
        wtl[o] = l;
    }
}

// ---------------- fused GEMM (128x128, m97 structure; measured 935 TF) ----------------
// O = relu(A_self*W_self + A_mean*W_neigh + bias) -> hi/lo
__global__ __launch_bounds__(256, 2) void k_gemm(
    const unsigned short* __restrict__ AsH, const unsigned short* __restrict__ AsL,
    const unsigned short* __restrict__ AmH, const unsigned short* __restrict__ AmL,
    const unsigned short* __restrict__ BH,  const unsigned short* __restrict__ BL,
    const float* __restrict__ bias,
    unsigned short* __restrict__ OH, unsigned short* __restrict__ OL, int ktiles) {
    __shared__ __align__(16) unsigned short lds[4 * 128 * 64];   // Ahi|Alo|Bhi|Blo, 64 KiB
    const int tid = threadIdx.x;
    const int wave = tid >> 6, lane = tid & 63;
    const int g = blockIdx.x;
    const int tm = g / GN, tn = g % GN;

    // staging coords: dest chunk = tid&7, source chunk XOR-swizzled (involution)
    const int srow = tid >> 3;                      // 0..31
    const int sc = (tid & 7) ^ (srow & 7);
    size_t aOff[4], bOff[4];
    #pragma unroll
    for (int j = 0; j < 4; j++) {
        int row = j * 32 + srow;
        aOff[j] = (size_t)(tm * 128 + row) * KP + sc * 8;
        bOff[j] = (size_t)(tn * 128 + row) * K2 + sc * 8;
    }
    char* ldsB = (char*)lds;
    const int dstBase = wave * 1024;

    const int wr = wave >> 1, wc = wave & 1;
    const int frow = lane & 15, fk = lane >> 4;
    int aFo[2][4], bFo[2][4];
    #pragma unroll
    for (int s = 0; s < 2; s++) {
        #pragma unroll
        for (int i = 0; i < 4; i++) {
            int ra = wr * 64 + i * 16 + frow;
            aFo[s][i] = ra * 64 + (((s * 4 + fk) ^ (ra & 7)) * 8);
            int rb = wc * 64 + i * 16 + frow;
            bFo[s][i] = rb * 64 + (((s * 4 + fk) ^ (rb & 7)) * 8);
        }
    }

    f32x4 acc[4][4];
    #pragma unroll
    for (int i = 0; i < 4; i++)
        #pragma unroll
        for (int j = 0; j < 4; j++) acc[i][j] = (f32x4){0.f, 0.f, 0.f, 0.f};

    for (int kt = 0; kt < ktiles; kt++) {
        const unsigned short *Ah, *Al;
        int kA;
        if (kt < KT_SEG) { Ah = AsH; Al = AsL; kA = kt * 64; }
        else             { Ah = AmH; Al = AmL; kA = (kt - KT_SEG) * 64; }
        const int kB = kt * 64;
        #pragma unroll
        for (int j = 0; j < 4; j++) {
            __builtin_amdgcn_global_load_lds((as1_cvoid*)(Ah + aOff[j] + kA),
                (as3_void*)(ldsB + 0 * 16384 + j * 4096 + dstBase), 16, 0, 0);
            __builtin_amdgcn_global_load_lds((as1_cvoid*)(Al + aOff[j] + kA),
                (as3_void*)(ldsB + 1 * 16384 + j * 4096 + dstBase), 16, 0, 0);
            __builtin_amdgcn_global_load_lds((as1_cvoid*)(BH + bOff[j] + kB),
                (as3_void*)(ldsB + 2 * 16384 + j * 4096 + dstBase), 16, 0, 0);
            __builtin_amdgcn_global_load_lds((as1_cvoid*)(BL + bOff[j] + kB),
                (as3_void*)(ldsB + 3 * 16384 + j * 4096 + dstBase), 16, 0, 0);
        }
        __syncthreads();
        #pragma unroll
        for (int s = 0; s < 2; s++) {
            short8 ah[4], al[4], bh[4], bl[4];
            #pragma unroll
            for (int i = 0; i < 4; i++) {
                ah[i] = *(const short8*)&lds[0 * 8192 + aFo[s][i]];
                al[i] = *(const short8*)&lds[1 * 8192 + aFo[s][i]];
                bh[i] = *(const short8*)&lds[2 * 8192 + bFo[s][i]];
                bl[i] = *(const short8*)&lds[3 * 8192 + bFo[s][i]];
            }
            #pragma unroll
            for (int mi = 0; mi < 4; mi++)
                #pragma unroll
                for (int ni = 0; ni < 4; ni++) {
                    acc[mi][ni] = __builtin_amdgcn_mfma_f32_16x16x32_bf16(ah[mi], bh[ni], acc[mi][ni], 0, 0, 0);
                    acc[mi][ni] = __builtin_amdgcn_mfma_f32_16x16x32_bf16(ah[mi], bl[ni], acc[mi][ni], 0, 0, 0);
                    acc[mi][ni] = __builtin_amdgcn_mfma_f32_16x16x32_bf16(al[mi], bh[ni], acc[mi][ni], 0, 0, 0);
                }
        }
        __syncthreads();
    }

    // epilogue: bias + relu + hi/lo decompose, zero pad cols
    const int r4 = (lane >> 4) * 4;
    #pragma unroll
    for (int ni = 0; ni < 4; ni++) {
        int gn = tn * 128 + wc * 64 + ni * 16 + (lane & 15);
        bool valid = gn < DIM;
        float bv = valid ? bias[gn] : 0.f;
        #pragma unroll
        for (int mi = 0; mi < 4; mi++) {
            int gmBase = tm * 128 + wr * 64 + mi * 16 + r4;
            #pragma unroll
            for (int rg = 0; rg < 4; rg++) {
                float v = acc[mi][ni][rg] + bv;
                v = fmaxf(v, 0.f);
                if (!valid) v = 0.f;
                size_t o = (size_t)(gmBase + rg) * KP + gn;
                unsigned short h = f2bf(v);
                OH[o] = h;
                OL[o] = f2bf(v - bf2f(h));
            }
        }
    }
}

// ---------------- final head: out = h @ Wc2 + bc2 ----------------
__global__ __launch_bounds__(256) void k_head(
    const unsigned short* __restrict__ HH, const unsigned short* __restrict__ HL,
    const float* __restrict__ W, const float* __restrict__ b, float* __restrict__ out) {
    const int m = blockIdx.x;
    const int t = threadIdx.x;
    const unsigned short* rh = HH + (size_t)m * KP;
    const unsigned short* rl = HL + (size_t)m * KP;
    float acc[NCLS];
    #pragma unroll
    for (int c = 0; c < NCLS; c++) acc[c] = 0.f;
    for (int j = 0; j < 5; j++) {
        int k0 = (j * 256 + t) * 2;
        if (k0 >= DIM) continue;
        unsigned hv = *(const unsigned*)(rh + k0);
        unsigned lv = *(const unsigned*)(rl + k0);
        float v0 = bf2f((unsigned short)(hv & 0xFFFFu)) + bf2f((unsigned short)(lv & 0xFFFFu));
        float v1 = bf2f((unsigned short)(hv >> 16)) + bf2f((unsigned short)(lv >> 16));
        const float* w0 = W + (size_t)k0 * NCLS;
        #pragma unroll
        for (int c = 0; c < NCLS; c++) acc[c] += v0 * w0[c] + v1 * w0[NCLS + c];
    }
    #pragma unroll
    for (int o = 32; o > 0; o >>= 1)
        #pragma unroll
        for (int c = 0; c < NCLS; c++) acc[c] += __shfl_down(acc[c], o);
    __shared__ float red[4][NCLS];
    if ((t & 63) == 0)
        #pragma unroll
        for (int c = 0; c < NCLS; c++) red[t >> 6][c] = acc[c];
    __syncthreads();
    if (t < NCLS)
        out[(size_t)m * NCLS + t] = red[0][t] + red[1][t] + red[2][t] + red[3][t] + b[t];
}

extern "C" void kernel_launch(void* const* d_in, const int* in_sizes, int n_in,
                              void* d_out, int out_size, void* d_ws, size_t ws_size,
                              hipStream_t stream) {
    const float* x   = (const float*)d_in[0];
    const int* ei    = (const int*)d_in[1];   // int32 (JAX default x64-disabled)
    const float* W1s = (const float*)d_in[2];
    const float* W1n = (const float*)d_in[3];
    const float* b1  = (const float*)d_in[4];
    const float* W2s = (const float*)d_in[5];
    const float* W2n = (const float*)d_in[6];
    const float* b2  = (const float*)d_in[7];
    const float* Wc1 = (const float*)d_in[8];
    const float* bc1 = (const float*)d_in[9];
    const float* Wc2 = (const float*)d_in[10];
    const float* bc2 = (const float*)d_in[11];

    char* p = (char*)d_ws;
    auto nxt = [&](size_t bytes) -> char* {
        char* r = p;
        p += (bytes + 255) & ~(size_t)255;
        return r;
    };
    const size_t PLB = (size_t)MP * KP * sizeof(unsigned short);   // 52.4 MB
    unsigned short* F0H = (unsigned short*)nxt(PLB);
    unsigned short* F0L = (unsigned short*)nxt(PLB);
    unsigned short* F1H = (unsigned short*)nxt(PLB);
    unsigned short* F1L = (unsigned short*)nxt(PLB);
    unsigned short* FMH = (unsigned short*)nxt(PLB);
    unsigned short* FML = (unsigned short*)nxt(PLB);
    const size_t WTB = (size_t)KP * K2 * sizeof(unsigned short);   // 26.2 MB
    unsigned short* WTH = (unsigned short*)nxt(WTB);
    unsigned short* WTL = (unsigned short*)nxt(WTB);
    int* deg = (int*)nxt(NNODES * 4);
    int* off = (int*)nxt((NNODES + 1) * 4);
    int* cur = (int*)nxt(NNODES * 4);
    int* csr = (int*)nxt(NEDGES * 4);

    hipMemsetAsync(deg, 0, NNODES * 4, stream);
    hipMemsetAsync(cur, 0, NNODES * 4, stream);

    k_deg<<<(NEDGES + 255) / 256, 256, 0, stream>>>(ei, deg);
    k_scan<<<1, 1024, 0, stream>>>(deg, off);
    k_fill<<<(NEDGES + 255) / 256, 256, 0, stream>>>(ei, off, cur, csr);

    k_cvt_x<<<(int)(((size_t)MP * (KP / 4) + 255) / 256), 256, 0, stream>>>(x, F0H, F0L);

    // layer 1
    k_agg<<<NNODES, 320, 0, stream>>>(F0H, F0L, off, csr, deg, FMH, FML);
    k_cvt_w<<<dim3(40, 40), 256, 0, stream>>>(W1s, WTH, WTL, 0);
    k_cvt_w<<<dim3(40, 40), 256, 0, stream>>>(W1n, WTH, WTL, 1);
    k_gemm<<<80 * GN, 256, 0, stream>>>(F0H, F0L, FMH, FML, WTH, WTL, b1, F1H, F1L, 80);

    // layer 2
    k_agg<<<NNODES, 320, 0, stream>>>(F1H, F1L, off, csr, deg, FMH, FML);
    k_cvt_w<<<dim3(40, 40), 256, 0, stream>>>(W2s, WTH, WTL, 0);
    k_cvt_w<<<dim3(40, 40), 256, 0, stream>>>(W2n, WTH, WTL, 1);
    k_gemm<<<80 * GN, 256, 0, stream>>>(F1H, F1L, FMH, FML, WTH, WTL, b2, F0H, F0L, 80);

    // classifier hidden (ktiles=40 -> mean planes never read; pass valid ptrs)
    k_cvt_w<<<dim3(40, 40), 256, 0, stream>>>(Wc1, WTH, WTL, 0);
    k_gemm<<<80 * GN, 256, 0, stream>>>(F0H, F0L, F0H, F0L, WTH, WTL, bc1, F1H, F1L, 40);

    // head
    k_head<<<NNODES, 256, 0, stream>>>(F1H, F1L, Wc2, bc2, (float*)d_out);
}

// Round 12
// 2885.722 us; speedup vs baseline: 1.0991x; 1.0409x over previous
//
#include <hip/hip_runtime.h>
#include <stdint.h>

#define NNODES 10000
#define NEDGES 160000
#define DIM    2500
#define NCLS   16
#define KP     2560          // padded feature dim (40 * 64)
#define MP     10240         // padded rows (80 * 128)
#define K2     5120          // concat K for layer GEMMs
#define GN     20            // N tiles (2560 / 128)
#define KT_SEG 40            // K-steps per segment (2560 / 64)

typedef __attribute__((ext_vector_type(8))) short short8;
typedef __attribute__((ext_vector_type(4))) float f32x4;
typedef __attribute__((address_space(3))) void as3_void;
typedef const __attribute__((address_space(1))) void as1_cvoid;

__device__ __forceinline__ unsigned short f2bf(float f) {
    unsigned u = __float_as_uint(f);
    u += 0x7FFFu + ((u >> 16) & 1u);            // RNE
    return (unsigned short)(u >> 16);
}
__device__ __forceinline__ float bf2f(unsigned short s) {
    return __uint_as_float(((unsigned)s) << 16);
}

// ---------------- CSR build (edge_index is int32) ----------------
__global__ void k_deg(const int* __restrict__ ei, int* __restrict__ deg) {
    int e = blockIdx.x * blockDim.x + threadIdx.x;
    if (e < NEDGES) atomicAdd(&deg[ei[NEDGES + e]], 1);
}

__global__ void k_scan(const int* __restrict__ deg, int* __restrict__ off) {
    __shared__ int s[1024];
    __shared__ int carryS;
    int t = threadIdx.x;
    if (t == 0) carryS = 0;
    __syncthreads();
    for (int c = 0; c < NNODES; c += 1024) {
        int i = c + t;
        int v = (i < NNODES) ? deg[i] : 0;
        s[t] = v;
        __syncthreads();
        for (int o = 1; o < 1024; o <<= 1) {
            int add = (t >= o) ? s[t - o] : 0;
            __syncthreads();
            s[t] += add;
            __syncthreads();
        }
        int base = carryS;
        if (i < NNODES) off[i] = base + s[t] - v;   // exclusive
        __syncthreads();
        if (t == 1023) carryS += s[1023];
        __syncthreads();
    }
    if (t == 0) off[NNODES] = carryS;
}

__global__ void k_fill(const int* __restrict__ ei, const int* __restrict__ off,
                       int* __restrict__ cur, int* __restrict__ csr) {
    int e = blockIdx.x * blockDim.x + threadIdx.x;
    if (e < NEDGES) {
        int s = ei[e];
        int d = ei[NEDGES + e];
        int p = atomicAdd(&cur[d], 1);
        csr[off[d] + p] = s;
    }
}

// ---------------- x -> hi/lo bf16 planes (padded, pads zeroed) ----------------
__global__ void k_cvt_x(const float* __restrict__ x,
                        unsigned short* __restrict__ hi, unsigned short* __restrict__ lo) {
    long long idx = (long long)blockIdx.x * blockDim.x + threadIdx.x;  // float4 index
    const int C4 = KP / 4;                                             // 640
    if (idx >= (long long)MP * C4) return;
    int row = (int)(idx / C4), c4 = (int)(idx % C4);
    int k = c4 * 4;
    float vv[4] = {0.f, 0.f, 0.f, 0.f};
    if (row < NNODES && k < DIM) {
        float4 v = *(const float4*)(x + (size_t)row * DIM + k);
        vv[0] = v.x; vv[1] = v.y; vv[2] = v.z; vv[3] = v.w;
    }
    unsigned hw[2], lw[2];
    for (int j = 0; j < 2; j++) {
        unsigned short h0 = f2bf(vv[2*j]);     unsigned short l0 = f2bf(vv[2*j]   - bf2f(h0));
        unsigned short h1 = f2bf(vv[2*j+1]);   unsigned short l1 = f2bf(vv[2*j+1] - bf2f(h1));
        hw[j] = (unsigned)h0 | ((unsigned)h1 << 16);
        lw[j] = (unsigned)l0 | ((unsigned)l1 << 16);
    }
    *(uint2*)(hi + (size_t)row * KP + k) = make_uint2(hw[0], hw[1]);
    *(uint2*)(lo + (size_t)row * KP + k) = make_uint2(lw[0], lw[1]);
}

// ---------------- mean aggregation over in-neighbors (2-edge unrolled) ----------------
__global__ __launch_bounds__(320) void k_agg(
    const unsigned short* __restrict__ shi, const unsigned short* __restrict__ slo,
    const int* __restrict__ off, const int* __restrict__ csr, const int* __restrict__ deg,
    unsigned short* __restrict__ mhi, unsigned short* __restrict__ mlo) {
    int d = blockIdx.x;
    int t = threadIdx.x;                     // owns 8 elems at k = t*8
    int s0 = off[d], s1 = off[d + 1];
    float acc[8];
    #pragma unroll
    for (int i = 0; i < 8; i++) acc[i] = 0.f;
    int e = s0;
    for (; e + 2 <= s1; e += 2) {
        int sa = csr[e], sb = csr[e + 1];
        uint4 ha = *((const uint4*)(shi + (size_t)sa * KP) + t);
        uint4 la = *((const uint4*)(slo + (size_t)sa * KP) + t);
        uint4 hb = *((const uint4*)(shi + (size_t)sb * KP) + t);
        uint4 lb = *((const uint4*)(slo + (size_t)sb * KP) + t);
        unsigned hua[4] = {ha.x, ha.y, ha.z, ha.w};
        unsigned lua[4] = {la.x, la.y, la.z, la.w};
        unsigned hub[4] = {hb.x, hb.y, hb.z, hb.w};
        unsigned lub[4] = {lb.x, lb.y, lb.z, lb.w};
        #pragma unroll
        for (int j = 0; j < 4; j++) {
            acc[2*j]   += bf2f((unsigned short)(hua[j] & 0xFFFFu)) + bf2f((unsigned short)(lua[j] & 0xFFFFu))
                        + bf2f((unsigned short)(hub[j] & 0xFFFFu)) + bf2f((unsigned short)(lub[j] & 0xFFFFu));
            acc[2*j+1] += bf2f((unsigned short)(hua[j] >> 16))     + bf2f((unsigned short)(lua[j] >> 16))
                        + bf2f((unsigned short)(hub[j] >> 16))     + bf2f((unsigned short)(lub[j] >> 16));
        }
    }
    for (; e < s1; e++) {
        int s = csr[e];
        uint4 hv = *((const uint4*)(shi + (size_t)s * KP) + t);
        uint4 lv = *((const uint4*)(slo + (size_t)s * KP) + t);
        unsigned hu[4] = {hv.x, hv.y, hv.z, hv.w};
        unsigned lu[4] = {lv.x, lv.y, lv.z, lv.w};
        #pragma unroll
        for (int j = 0; j < 4; j++) {
            acc[2*j]   += bf2f((unsigned short)(hu[j] & 0xFFFFu)) + bf2f((unsigned short)(lu[j] & 0xFFFFu));
            acc[2*j+1] += bf2f((unsigned short)(hu[j] >> 16))     + bf2f((unsigned short)(lu[j] >> 16));
        }
    }
    int dg = deg[d];
    float inv = 1.0f / (float)(dg > 1 ? dg : 1);
    unsigned oh[4], ol[4];
    #pragma unroll
    for (int j = 0; j < 4; j++) {
        float m0 = acc[2*j] * inv, m1 = acc[2*j+1] * inv;
        unsigned short h0 = f2bf(m0); unsigned short l0 = f2bf(m0 - bf2f(h0));
        unsigned short h1 = f2bf(m1); unsigned short l1 = f2bf(m1 - bf2f(h1));
        oh[j] = (unsigned)h0 | ((unsigned)h1 << 16);
        ol[j] = (unsigned)l0 | ((unsigned)l1 << 16);
    }
    *((uint4*)(mhi + (size_t)d * KP) + t) = make_uint4(oh[0], oh[1], oh[2], oh[3]);
    *((uint4*)(mlo + (size_t)d * KP) + t) = make_uint4(ol[0], ol[1], ol[2], ol[3]);
}

// ---------------- W (K x N fp32) -> WT (N x K2, hi/lo bf16), transposed ----------------
__global__ __launch_bounds__(256) void k_cvt_w(const float* __restrict__ W,
                                               unsigned short* __restrict__ wth,
                                               unsigned short* __restrict__ wtl, int seg) {
    __shared__ float tile[64][65];
    int k0 = blockIdx.x * 64, n0 = blockIdx.y * 64;
    int t = threadIdx.x;
    for (int j = 0; j < 16; j++) {
        int lin = t + j * 256;
        int kk = lin >> 6, nn = lin & 63;
        int gk = k0 + kk, gn = n0 + nn;
        tile[kk][nn] = (gk < DIM && gn < DIM) ? W[(size_t)gk * DIM + gn] : 0.f;
    }
    __syncthreads();
    for (int j = 0; j < 16; j++) {
        int lin = t + j * 256;
        int nn = lin >> 6, kk = lin & 63;
        float v = tile[kk][nn];
        unsigned short h = f2bf(v);
        unsigned short l = f2bf(v - bf2f(h));
        size_t o = (size_t)(n0 + nn) * K2 + (size_t)seg * KP + (k0 + kk);
        wth[o] = h;
        wtl[o] = l;
    }
}

// ---------------- fused GEMM (128x128, m97 structure; measured 935 TF) ----------------
// O = relu(A_self*W_self + A_mean*W_neigh + bias) -> hi/lo
// + chunked XCD swizzle (T1): XCD x owns 200 contiguous tiles -> A-panel L2 reuse.
__global__ __launch_bounds__(256, 2) void k_gemm(
    const unsigned short* __restrict__ AsH, const unsigned short* __restrict__ AsL,
    const unsigned short* __restrict__ AmH, const unsigned short* __restrict__ AmL,
    const unsigned short* __restrict__ BH,  const unsigned short* __restrict__ BL,
    const float* __restrict__ bias,
    unsigned short* __restrict__ OH, unsigned short* __restrict__ OL, int ktiles) {
    __shared__ __align__(16) unsigned short lds[4 * 128 * 64];   // Ahi|Alo|Bhi|Blo, 64 KiB
    const int tid = threadIdx.x;
    const int wave = tid >> 6, lane = tid & 63;
    // chunked XCD swizzle: nwg = 1600, 1600 % 8 == 0 -> bijective simple form.
    // dispatch round-robins blockIdx%8 across XCDs; remap so XCD x gets
    // contiguous tile ids [x*200, (x+1)*200): 20 consecutive tiles share one
    // 1.3 MB A panel -> L2-resident -> shorter global_load_lds drain.
    const int nwg = gridDim.x;
    const int g = (blockIdx.x & 7) * (nwg >> 3) + (blockIdx.x >> 3);
    const int tm = g / GN, tn = g % GN;

    // staging coords: dest chunk = tid&7, source chunk XOR-swizzled (involution)
    const int srow = tid >> 3;                      // 0..31
    const int sc = (tid & 7) ^ (srow & 7);
    size_t aOff[4], bOff[4];
    #pragma unroll
    for (int j = 0; j < 4; j++) {
        int row = j * 32 + srow;
        aOff[j] = (size_t)(tm * 128 + row) * KP + sc * 8;
        bOff[j] = (size_t)(tn * 128 + row) * K2 + sc * 8;
    }
    char* ldsB = (char*)lds;
    const int dstBase = wave * 1024;

    const int wr = wave >> 1, wc = wave & 1;
    const int frow = lane & 15, fk = lane >> 4;
    int aFo[2][4], bFo[2][4];
    #pragma unroll
    for (int s = 0; s < 2; s++) {
        #pragma unroll
        for (int i = 0; i < 4; i++) {
            int ra = wr * 64 + i * 16 + frow;
            aFo[s][i] = ra * 64 + (((s * 4 + fk) ^ (ra & 7)) * 8);
            int rb = wc * 64 + i * 16 + frow;
            bFo[s][i] = rb * 64 + (((s * 4 + fk) ^ (rb & 7)) * 8);
        }
    }

    f32x4 acc[4][4];
    #pragma unroll
    for (int i = 0; i < 4; i++)
        #pragma unroll
        for (int j = 0; j < 4; j++) acc[i][j] = (f32x4){0.f, 0.f, 0.f, 0.f};

    for (int kt = 0; kt < ktiles; kt++) {
        const unsigned short *Ah, *Al;
        int kA;
        if (kt < KT_SEG) { Ah = AsH; Al = AsL; kA = kt * 64; }
        else             { Ah = AmH; Al = AmL; kA = (kt - KT_SEG) * 64; }
        const int kB = kt * 64;
        #pragma unroll
        for (int j = 0; j < 4; j++) {
            __builtin_amdgcn_global_load_lds((as1_cvoid*)(Ah + aOff[j] + kA),
                (as3_void*)(ldsB + 0 * 16384 + j * 4096 + dstBase), 16, 0, 0);
            __builtin_amdgcn_global_load_lds((as1_cvoid*)(Al + aOff[j] + kA),
                (as3_void*)(ldsB + 1 * 16384 + j * 4096 + dstBase), 16, 0, 0);
            __builtin_amdgcn_global_load_lds((as1_cvoid*)(BH + bOff[j] + kB),
                (as3_void*)(ldsB + 2 * 16384 + j * 4096 + dstBase), 16, 0, 0);
            __builtin_amdgcn_global_load_lds((as1_cvoid*)(BL + bOff[j] + kB),
                (as3_void*)(ldsB + 3 * 16384 + j * 4096 + dstBase), 16, 0, 0);
        }
        __syncthreads();
        #pragma unroll
        for (int s = 0; s < 2; s++) {
            short8 ah[4], al[4], bh[4], bl[4];
            #pragma unroll
            for (int i = 0; i < 4; i++) {
                ah[i] = *(const short8*)&lds[0 * 8192 + aFo[s][i]];
                al[i] = *(const short8*)&lds[1 * 8192 + aFo[s][i]];
                bh[i] = *(const short8*)&lds[2 * 8192 + bFo[s][i]];
                bl[i] = *(const short8*)&lds[3 * 8192 + bFo[s][i]];
            }
            #pragma unroll
            for (int mi = 0; mi < 4; mi++)
                #pragma unroll
                for (int ni = 0; ni < 4; ni++) {
                    acc[mi][ni] = __builtin_amdgcn_mfma_f32_16x16x32_bf16(ah[mi], bh[ni], acc[mi][ni], 0, 0, 0);
                    acc[mi][ni] = __builtin_amdgcn_mfma_f32_16x16x32_bf16(ah[mi], bl[ni], acc[mi][ni], 0, 0, 0);
                    acc[mi][ni] = __builtin_amdgcn_mfma_f32_16x16x32_bf16(al[mi], bh[ni], acc[mi][ni], 0, 0, 0);
                }
        }
        __syncthreads();
    }

    // epilogue: bias + relu + hi/lo decompose, zero pad cols
    const int r4 = (lane >> 4) * 4;
    #pragma unroll
    for (int ni = 0; ni < 4; ni++) {
        int gn = tn * 128 + wc * 64 + ni * 16 + (lane & 15);
        bool valid = gn < DIM;
        float bv = valid ? bias[gn] : 0.f;
        #pragma unroll
        for (int mi = 0; mi < 4; mi++) {
            int gmBase = tm * 128 + wr * 64 + mi * 16 + r4;
            #pragma unroll
            for (int rg = 0; rg < 4; rg++) {
                float v = acc[mi][ni][rg] + bv;
                v = fmaxf(v, 0.f);
                if (!valid) v = 0.f;
                size_t o = (size_t)(gmBase + rg) * KP + gn;
                unsigned short h = f2bf(v);
                OH[o] = h;
                OL[o] = f2bf(v - bf2f(h));
            }
        }
    }
}

// ---------------- final head: out = h @ Wc2 + bc2 ----------------
__global__ __launch_bounds__(256) void k_head(
    const unsigned short* __restrict__ HH, const unsigned short* __restrict__ HL,
    const float* __restrict__ W, const float* __restrict__ b, float* __restrict__ out) {
    const int m = blockIdx.x;
    const int t = threadIdx.x;
    const unsigned short* rh = HH + (size_t)m * KP;
    const unsigned short* rl = HL + (size_t)m * KP;
    float acc[NCLS];
    #pragma unroll
    for (int c = 0; c < NCLS; c++) acc[c] = 0.f;
    for (int j = 0; j < 5; j++) {
        int k0 = (j * 256 + t) * 2;
        if (k0 >= DIM) continue;
        unsigned hv = *(const unsigned*)(rh + k0);
        unsigned lv = *(const unsigned*)(rl + k0);
        float v0 = bf2f((unsigned short)(hv & 0xFFFFu)) + bf2f((unsigned short)(lv & 0xFFFFu));
        float v1 = bf2f((unsigned short)(hv >> 16)) + bf2f((unsigned short)(lv >> 16));
        const float* w0 = W + (size_t)k0 * NCLS;
        #pragma unroll
        for (int c = 0; c < NCLS; c++) acc[c] += v0 * w0[c] + v1 * w0[NCLS + c];
    }
    #pragma unroll
    for (int o = 32; o > 0; o >>= 1)
        #pragma unroll
        for (int c = 0; c < NCLS; c++) acc[c] += __shfl_down(acc[c], o);
    __shared__ float red[4][NCLS];
    if ((t & 63) == 0)
        #pragma unroll
        for (int c = 0; c < NCLS; c++) red[t >> 6][c] = acc[c];
    __syncthreads();
    if (t < NCLS)
        out[(size_t)m * NCLS + t] = red[0][t] + red[1][t] + red[2][t] + red[3][t] + b[t];
}

extern "C" void kernel_launch(void* const* d_in, const int* in_sizes, int n_in,
                              void* d_out, int out_size, void* d_ws, size_t ws_size,
                              hipStream_t stream) {
    const float* x   = (const float*)d_in[0];
    const int* ei    = (const int*)d_in[1];   // int32 (JAX default x64-disabled)
    const float* W1s = (const float*)d_in[2];
    const float* W1n = (const float*)d_in[3];
    const float* b1  = (const float*)d_in[4];
    const float* W2s = (const float*)d_in[5];
    const float* W2n = (const float*)d_in[6];
    const float* b2  = (const float*)d_in[7];
    const float* Wc1 = (const float*)d_in[8];
    const float* bc1 = (const float*)d_in[9];
    const float* Wc2 = (const float*)d_in[10];
    const float* bc2 = (const float*)d_in[11];

    char* p = (char*)d_ws;
    auto nxt = [&](size_t bytes) -> char* {
        char* r = p;
        p += (bytes + 255) & ~(size_t)255;
        return r;
    };
    const size_t PLB = (size_t)MP * KP * sizeof(unsigned short);   // 52.4 MB
    unsigned short* F0H = (unsigned short*)nxt(PLB);
    unsigned short* F0L = (unsigned short*)nxt(PLB);
    unsigned short* F1H = (unsigned short*)nxt(PLB);
    unsigned short* F1L = (unsigned short*)nxt(PLB);
    unsigned short* FMH = (unsigned short*)nxt(PLB);
    unsigned short* FML = (unsigned short*)nxt(PLB);
    const size_t WTB = (size_t)KP * K2 * sizeof(unsigned short);   // 26.2 MB
    unsigned short* WTH = (unsigned short*)nxt(WTB);
    unsigned short* WTL = (unsigned short*)nxt(WTB);
    int* deg = (int*)nxt(NNODES * 4);
    int* off = (int*)nxt((NNODES + 1) * 4);
    int* cur = (int*)nxt(NNODES * 4);
    int* csr = (int*)nxt(NEDGES * 4);

    hipMemsetAsync(deg, 0, NNODES * 4, stream);
    hipMemsetAsync(cur, 0, NNODES * 4, stream);

    k_deg<<<(NEDGES + 255) / 256, 256, 0, stream>>>(ei, deg);
    k_scan<<<1, 1024, 0, stream>>>(deg, off);
    k_fill<<<(NEDGES + 255) / 256, 256, 0, stream>>>(ei, off, cur, csr);

    k_cvt_x<<<(int)(((size_t)MP * (KP / 4) + 255) / 256), 256, 0, stream>>>(x, F0H, F0L);

    // layer 1
    k_agg<<<NNODES, 320, 0, stream>>>(F0H, F0L, off, csr, deg, FMH, FML);
    k_cvt_w<<<dim3(40, 40), 256, 0, stream>>>(W1s, WTH, WTL, 0);
    k_cvt_w<<<dim3(40, 40), 256, 0, stream>>>(W1n, WTH, WTL, 1);
    k_gemm<<<80 * GN, 256, 0, stream>>>(F0H, F0L, FMH, FML, WTH, WTL, b1, F1H, F1L, 80);

    // layer 2
    k_agg<<<NNODES, 320, 0, stream>>>(F1H, F1L, off, csr, deg, FMH, FML);
    k_cvt_w<<<dim3(40, 40), 256, 0, stream>>>(W2s, WTH, WTL, 0);
    k_cvt_w<<<dim3(40, 40), 256, 0, stream>>>(W2n, WTH, WTL, 1);
    k_gemm<<<80 * GN, 256, 0, stream>>>(F1H, F1L, FMH, FML, WTH, WTL, b2, F0H, F0L, 80);

    // classifier hidden (ktiles=40 -> mean planes never read; pass valid ptrs)
    k_cvt_w<<<dim3(40, 40), 256, 0, stream>>>(Wc1, WTH, WTL, 0);
    k_gemm<<<80 * GN, 256, 0, stream>>>(F0H, F0L, F0H, F0L, WTH, WTL, bc1, F1H, F1L, 40);

    // head
    k_head<<<NNODES, 256, 0, stream>>>(F1H, F1L, Wc2, bc2, (float*)d_out);
}